// Round 4
// baseline (732.234 us; speedup 1.0000x reference)
//
#include <hip/hip_runtime.h>

// Problem dims (fixed by reference)
#define BB   2
#define NBB  32
#define PP   128
#define FF   32
#define HH   32
#define NO   8
#define OUTC 32
#define NROWS (BB*NBB*PP)   // 8192
#define ICHUNK 4

__device__ __forceinline__ float elu_f(float x){
    return x > 0.0f ? x : (__expf(x) - 1.0f);
}

// Kernel A: node MLP + projection to pa/pb. One thread per row.
// pa gets pair_b0 folded in so kernel B's h0 = elu(pa_i + pb_j).
__global__ __launch_bounds__(256) void node_kernel(
    const float* __restrict__ x,  const float* __restrict__ msk,
    const float* __restrict__ w0, const float* __restrict__ b0,
    const float* __restrict__ w1, const float* __restrict__ b1,
    const float* __restrict__ w2, const float* __restrict__ b2,
    const float* __restrict__ pw0,const float* __restrict__ pb0,
    float* __restrict__ pa, float* __restrict__ pb)
{
    int row = blockIdx.x*256 + threadIdx.x;
    if (row >= NROWS) return;

    float xr[FF];
    const float4* xp = reinterpret_cast<const float4*>(x + (size_t)row*FF);
#pragma unroll
    for (int q=0;q<FF/4;q++){ float4 v=xp[q]; xr[4*q]=v.x; xr[4*q+1]=v.y; xr[4*q+2]=v.z; xr[4*q+3]=v.w; }

    float h[HH];
#pragma unroll
    for (int k=0;k<HH;k++) h[k]=b0[k];
#pragma unroll
    for (int m=0;m<FF;m++){
        float xm = xr[m];
#pragma unroll
        for (int k=0;k<HH;k++) h[k] += xm * w0[m*HH+k];
    }
#pragma unroll
    for (int k=0;k<HH;k++) h[k]=elu_f(h[k]);

    float g[HH];
#pragma unroll
    for (int k=0;k<HH;k++) g[k]=b1[k];
#pragma unroll
    for (int m=0;m<HH;m++){
        float hm=h[m];
#pragma unroll
        for (int k=0;k<HH;k++) g[k] += hm * w1[m*HH+k];
    }
#pragma unroll
    for (int k=0;k<HH;k++) g[k]=elu_f(g[k]);

    float mk = msk[row];
    float npj[NO];
#pragma unroll
    for (int k=0;k<NO;k++) npj[k]=b2[k];
#pragma unroll
    for (int m=0;m<HH;m++){
        float gm=g[m];
#pragma unroll
        for (int k=0;k<NO;k++) npj[k] += gm * w2[m*NO+k];
    }
#pragma unroll
    for (int k=0;k<NO;k++) npj[k]=elu_f(npj[k])*mk;

    float pav[HH], pbv[HH];
#pragma unroll
    for (int k=0;k<HH;k++){ pav[k]=pb0[k]; pbv[k]=0.0f; }
#pragma unroll
    for (int m=0;m<NO;m++){
        float nm=npj[m];
#pragma unroll
        for (int k=0;k<HH;k++){
            pav[k] += nm * pw0[m*HH+k];
            pbv[k] += nm * pw0[(NO+m)*HH+k];
        }
    }
    float4* pap = reinterpret_cast<float4*>(pa + (size_t)row*HH);
    float4* pbp = reinterpret_cast<float4*>(pb + (size_t)row*HH);
#pragma unroll
    for (int q=0;q<HH/4;q++){
        pap[q]=make_float4(pav[4*q],pav[4*q+1],pav[4*q+2],pav[4*q+3]);
        pbp[q]=make_float4(pbv[4*q],pbv[4*q+1],pbv[4*q+2],pbv[4*q+3]);
    }
}

// Kernel B: one thread = one (i,j) pair, full 32->32->32 MLP in registers.
// Weights live in LDS (eviction-immune vs the 134 MB output write stream that
// thrashed L1/L2 in R1: FETCH_SIZE was 6.6 GB -> 0.95 GB in R3).
// Regular float4 stores: L2 write-combining merges the 16B/lane stride-128B
// pattern into full lines (R1 WRITE_SIZE was exactly 131072 KB); nontemporal
// stores bypassed L2 and amplified writes 6.4x (R3).
__global__ __launch_bounds__(128, 2) void pair_kernel(
    const float* __restrict__ pa, const float* __restrict__ pb,
    const float* __restrict__ w1, const float* __restrict__ b1,
    const float* __restrict__ w2, const float* __restrict__ b2,
    float* __restrict__ out)
{
    __shared__ float w1s[HH*HH];      // 4 KB
    __shared__ float w2s[HH*OUTC];    // 4 KB
    __shared__ float b1s[HH];
    __shared__ float b2s[OUTC];
    __shared__ float pas[ICHUNK*HH];  // pa rows for this block (pair_b0 folded)

    const int bnb = blockIdx.x / (PP/ICHUNK);
    const int i0  = (blockIdx.x % (PP/ICHUNK)) * ICHUNK;
    const int t   = threadIdx.x;
    const int j   = t;                 // 0..127 -> pb row

    // Cooperative staging (vectorized): 2*1024 + 64 + 128 floats.
    {
        const float4* s1 = reinterpret_cast<const float4*>(w1);
        const float4* s2 = reinterpret_cast<const float4*>(w2);
        float4* d1 = reinterpret_cast<float4*>(w1s);
        float4* d2 = reinterpret_cast<float4*>(w2s);
#pragma unroll
        for (int q=0;q<2;q++){ d1[t + 128*q] = s1[t + 128*q]; d2[t + 128*q] = s2[t + 128*q]; }
        if (t < HH)  b1s[t] = b1[t];
        else if (t < HH+OUTC) b2s[t-HH] = b2[t-HH];
        const float4* sp = reinterpret_cast<const float4*>(pa + ((size_t)bnb*PP + i0)*HH);
        float4* dp = reinterpret_cast<float4*>(pas);
        if (t < ICHUNK*HH/4) dp[t] = sp[t];
    }
    __syncthreads();

    // Per-thread pb row (coalesced: 128 consecutive rows per block).
    float vb[HH];
    const float4* pbp = reinterpret_cast<const float4*>(pb + ((size_t)bnb*PP + j)*HH);
#pragma unroll
    for (int q=0;q<HH/4;q++){ float4 v=pbp[q]; vb[4*q]=v.x; vb[4*q+1]=v.y; vb[4*q+2]=v.z; vb[4*q+3]=v.w; }

    for (int ii=0; ii<ICHUNK; ii++){
        const int i = i0+ii;

        float h0[HH];
#pragma unroll
        for (int m=0;m<HH;m++) h0[m] = elu_f(pas[ii*HH+m] + vb[m]);

        float h1[HH];
#pragma unroll
        for (int k=0;k<HH;k++) h1[k]=b1s[k];
#pragma unroll
        for (int m=0;m<HH;m++){
            float hm=h0[m];
#pragma unroll
            for (int k=0;k<HH;k++) h1[k] += hm * w1s[m*HH+k];
        }
#pragma unroll
        for (int k=0;k<HH;k++) h1[k]=elu_f(h1[k]);

        float o[OUTC];
#pragma unroll
        for (int k=0;k<OUTC;k++) o[k]=b2s[k];
#pragma unroll
        for (int m=0;m<HH;m++){
            float hm=h1[m];
#pragma unroll
            for (int k=0;k<OUTC;k++) o[k] += hm * w2s[m*OUTC+k];
        }

        float4* op = reinterpret_cast<float4*>(out + (((size_t)bnb*PP + i)*PP + j)*OUTC);
#pragma unroll
        for (int q=0;q<OUTC/4;q++)
            op[q]=make_float4(elu_f(o[4*q]),elu_f(o[4*q+1]),elu_f(o[4*q+2]),elu_f(o[4*q+3]));
    }
}

extern "C" void kernel_launch(void* const* d_in, const int* in_sizes, int n_in,
                              void* d_out, int out_size, void* d_ws, size_t ws_size,
                              hipStream_t stream) {
    const float* x    = (const float*)d_in[0];
    const float* msk  = (const float*)d_in[1];
    const float* nw0  = (const float*)d_in[2];
    const float* nb0  = (const float*)d_in[3];
    const float* nw1  = (const float*)d_in[4];
    const float* nb1  = (const float*)d_in[5];
    const float* nw2  = (const float*)d_in[6];
    const float* nb2  = (const float*)d_in[7];
    const float* pw0  = (const float*)d_in[8];
    const float* pb0  = (const float*)d_in[9];
    const float* pw1  = (const float*)d_in[10];
    const float* pb1  = (const float*)d_in[11];
    const float* pw2  = (const float*)d_in[12];
    const float* pb2  = (const float*)d_in[13];
    float* out = (float*)d_out;

    float* pa = (float*)d_ws;                       // 8192*32 floats = 1 MiB
    float* pb = pa + (size_t)NROWS*HH;              // +1 MiB

    node_kernel<<<NROWS/256, 256, 0, stream>>>(x, msk, nw0, nb0, nw1, nb1,
                                               nw2, nb2, pw0, pb0, pa, pb);
    pair_kernel<<<BB*NBB*(PP/ICHUNK), 128, 0, stream>>>(pa, pb, pw1, pb1,
                                                        pw2, pb2, out);
}

// Round 5
// 275.333 us; speedup vs baseline: 2.6594x; 2.6594x over previous
//
#include <hip/hip_runtime.h>

// Problem dims (fixed by reference)
#define BB   2
#define NBB  32
#define PP   128
#define FF   32
#define HH   32
#define NO   8
#define OUTC 32
#define NROWS (BB*NBB*PP)   // 8192
#define ICHUNK 4

__device__ __forceinline__ float elu_f(float x){
    return x > 0.0f ? x : (__expf(x) - 1.0f);
}

// Kernel A: node MLP + projection to pa/pb. One thread per row.
// pa gets pair_b0 folded in so kernel B's h0 = elu(pa_i + pb_j).
__global__ __launch_bounds__(256) void node_kernel(
    const float* __restrict__ x,  const float* __restrict__ msk,
    const float* __restrict__ w0, const float* __restrict__ b0,
    const float* __restrict__ w1, const float* __restrict__ b1,
    const float* __restrict__ w2, const float* __restrict__ b2,
    const float* __restrict__ pw0,const float* __restrict__ pb0,
    float* __restrict__ pa, float* __restrict__ pb)
{
    int row = blockIdx.x*256 + threadIdx.x;
    if (row >= NROWS) return;

    float xr[FF];
    const float4* xp = reinterpret_cast<const float4*>(x + (size_t)row*FF);
#pragma unroll
    for (int q=0;q<FF/4;q++){ float4 v=xp[q]; xr[4*q]=v.x; xr[4*q+1]=v.y; xr[4*q+2]=v.z; xr[4*q+3]=v.w; }

    float h[HH];
#pragma unroll
    for (int k=0;k<HH;k++) h[k]=b0[k];
#pragma unroll
    for (int m=0;m<FF;m++){
        float xm = xr[m];
#pragma unroll
        for (int k=0;k<HH;k++) h[k] += xm * w0[m*HH+k];
    }
#pragma unroll
    for (int k=0;k<HH;k++) h[k]=elu_f(h[k]);

    float g[HH];
#pragma unroll
    for (int k=0;k<HH;k++) g[k]=b1[k];
#pragma unroll
    for (int m=0;m<HH;m++){
        float hm=h[m];
#pragma unroll
        for (int k=0;k<HH;k++) g[k] += hm * w1[m*HH+k];
    }
#pragma unroll
    for (int k=0;k<HH;k++) g[k]=elu_f(g[k]);

    float mk = msk[row];
    float npj[NO];
#pragma unroll
    for (int k=0;k<NO;k++) npj[k]=b2[k];
#pragma unroll
    for (int m=0;m<HH;m++){
        float gm=g[m];
#pragma unroll
        for (int k=0;k<NO;k++) npj[k] += gm * w2[m*NO+k];
    }
#pragma unroll
    for (int k=0;k<NO;k++) npj[k]=elu_f(npj[k])*mk;

    float pav[HH], pbv[HH];
#pragma unroll
    for (int k=0;k<HH;k++){ pav[k]=pb0[k]; pbv[k]=0.0f; }
#pragma unroll
    for (int m=0;m<NO;m++){
        float nm=npj[m];
#pragma unroll
        for (int k=0;k<HH;k++){
            pav[k] += nm * pw0[m*HH+k];
            pbv[k] += nm * pw0[(NO+m)*HH+k];
        }
    }
    float4* pap = reinterpret_cast<float4*>(pa + (size_t)row*HH);
    float4* pbp = reinterpret_cast<float4*>(pb + (size_t)row*HH);
#pragma unroll
    for (int q=0;q<HH/4;q++){
        pap[q]=make_float4(pav[4*q],pav[4*q+1],pav[4*q+2],pav[4*q+3]);
        pbp[q]=make_float4(pbv[4*q],pbv[4*q+1],pbv[4*q+2],pbv[4*q+3]);
    }
}

// Kernel B: one thread = one (i,j) pair, full 32->32->32 MLP in registers.
// Weights in LDS (R1->R3: FETCH 6.6 GB -> 0.95 GB).
// Output staged through LDS so each global store instruction covers a
// CONTIGUOUS 1 KB span (64 lanes x 16 B). R3/R4 showed the direct per-pair
// store pattern (16 B per lane at 128 B stride) causes partial-line RMW in
// L2: WRITE_SIZE 131 MB -> 794 MB, FETCH +1 GB, kernel became HBM-bound.
__global__ __launch_bounds__(128, 2) void pair_kernel(
    const float* __restrict__ pa, const float* __restrict__ pb,
    const float* __restrict__ w1, const float* __restrict__ b1,
    const float* __restrict__ w2, const float* __restrict__ b2,
    float* __restrict__ out)
{
    __shared__ float w1s[HH*HH];      // 4 KB
    __shared__ float w2s[HH*OUTC];    // 4 KB
    __shared__ float b1s[HH];
    __shared__ float b2s[OUTC];
    __shared__ float pas[ICHUNK*HH];  // pa rows for this block (pair_b0 folded)
    __shared__ float4 outs[PP*OUTC/4]; // 16 KB: one i-row output tile, flat == global layout

    const int bnb = blockIdx.x / (PP/ICHUNK);
    const int i0  = (blockIdx.x % (PP/ICHUNK)) * ICHUNK;
    const int t   = threadIdx.x;
    const int j   = t;                 // 0..127 -> pb row

    // Cooperative staging (vectorized): 2*1024 + 64 + 128 floats.
    {
        const float4* s1 = reinterpret_cast<const float4*>(w1);
        const float4* s2 = reinterpret_cast<const float4*>(w2);
        float4* d1 = reinterpret_cast<float4*>(w1s);
        float4* d2 = reinterpret_cast<float4*>(w2s);
#pragma unroll
        for (int q=0;q<2;q++){ d1[t + 128*q] = s1[t + 128*q]; d2[t + 128*q] = s2[t + 128*q]; }
        if (t < HH)  b1s[t] = b1[t];
        else if (t < HH+OUTC) b2s[t-HH] = b2[t-HH];
        const float4* sp = reinterpret_cast<const float4*>(pa + ((size_t)bnb*PP + i0)*HH);
        float4* dp = reinterpret_cast<float4*>(pas);
        if (t < ICHUNK*HH/4) dp[t] = sp[t];
    }
    __syncthreads();

    // Per-thread pb row (coalesced: 128 consecutive rows per block).
    float vb[HH];
    const float4* pbp = reinterpret_cast<const float4*>(pb + ((size_t)bnb*PP + j)*HH);
#pragma unroll
    for (int q=0;q<HH/4;q++){ float4 v=pbp[q]; vb[4*q]=v.x; vb[4*q+1]=v.y; vb[4*q+2]=v.z; vb[4*q+3]=v.w; }

    for (int ii=0; ii<ICHUNK; ii++){
        const int i = i0+ii;

        float h0[HH];
#pragma unroll
        for (int m=0;m<HH;m++) h0[m] = elu_f(pas[ii*HH+m] + vb[m]);

        float h1[HH];
#pragma unroll
        for (int k=0;k<HH;k++) h1[k]=b1s[k];
#pragma unroll
        for (int m=0;m<HH;m++){
            float hm=h0[m];
#pragma unroll
            for (int k=0;k<HH;k++) h1[k] += hm * w1s[m*HH+k];
        }
#pragma unroll
        for (int k=0;k<HH;k++) h1[k]=elu_f(h1[k]);

        float o[OUTC];
#pragma unroll
        for (int k=0;k<OUTC;k++) o[k]=b2s[k];
#pragma unroll
        for (int m=0;m<HH;m++){
            float hm=h1[m];
#pragma unroll
            for (int k=0;k<OUTC;k++) o[k] += hm * w2s[m*OUTC+k];
        }

        // Stage this pair's 32 outputs into the LDS tile (layout == global).
        float4* orow = reinterpret_cast<float4*>(outs) + j*(OUTC/4);
#pragma unroll
        for (int q=0;q<OUTC/4;q++)
            orow[q] = make_float4(elu_f(o[4*q]),elu_f(o[4*q+1]),elu_f(o[4*q+2]),elu_f(o[4*q+3]));
        __syncthreads();

        // Cooperative coalesced writeout: each instruction = 1 KB contiguous.
        float4* dst = reinterpret_cast<float4*>(out + ((size_t)(bnb*PP + i))*PP*OUTC);
#pragma unroll
        for (int r=0;r<PP*OUTC/4/128;r++)
            dst[t + 128*r] = outs[t + 128*r];
        __syncthreads();   // outs reused next ii
    }
}

extern "C" void kernel_launch(void* const* d_in, const int* in_sizes, int n_in,
                              void* d_out, int out_size, void* d_ws, size_t ws_size,
                              hipStream_t stream) {
    const float* x    = (const float*)d_in[0];
    const float* msk  = (const float*)d_in[1];
    const float* nw0  = (const float*)d_in[2];
    const float* nb0  = (const float*)d_in[3];
    const float* nw1  = (const float*)d_in[4];
    const float* nb1  = (const float*)d_in[5];
    const float* nw2  = (const float*)d_in[6];
    const float* nb2  = (const float*)d_in[7];
    const float* pw0  = (const float*)d_in[8];
    const float* pb0  = (const float*)d_in[9];
    const float* pw1  = (const float*)d_in[10];
    const float* pb1  = (const float*)d_in[11];
    const float* pw2  = (const float*)d_in[12];
    const float* pb2  = (const float*)d_in[13];
    float* out = (float*)d_out;

    float* pa = (float*)d_ws;                       // 8192*32 floats = 1 MiB
    float* pb = pa + (size_t)NROWS*HH;              // +1 MiB

    node_kernel<<<NROWS/256, 256, 0, stream>>>(x, msk, nw0, nb0, nw1, nb1,
                                               nw2, nb2, pw0, pb0, pa, pb);
    pair_kernel<<<BB*NBB*(PP/ICHUNK), 128, 0, stream>>>(pa, pb, pw1, pb1,
                                                        pw2, pb2, out);
}

// Round 6
// 91.530 us; speedup vs baseline: 8.0000x; 3.0081x over previous
//
#include <hip/hip_runtime.h>

// Problem dims (fixed by reference)
#define BB   2
#define NBB  32
#define PP   128
#define FF   32
#define HH   32
#define NO   8
#define OUTC 32
#define NROWS (BB*NBB*PP)   // 8192

typedef float  f32x4 __attribute__((ext_vector_type(4)));
typedef short  s16x8 __attribute__((ext_vector_type(8)));
typedef unsigned int u32x4 __attribute__((ext_vector_type(4)));

__device__ __forceinline__ float elu_f(float x){
    return x > 0.0f ? x : (__expf(x) - 1.0f);
}
// round-to-nearest-even fp32 -> bf16 bits
__device__ __forceinline__ unsigned short bf16_hi(float f){
    unsigned u = __builtin_bit_cast(unsigned, f);
    unsigned r = u + 0x7FFFu + ((u >> 16) & 1u);
    return (unsigned short)(r >> 16);
}
__device__ __forceinline__ float bf16_to_f(unsigned short h){
    unsigned u = ((unsigned)h) << 16;
    return __builtin_bit_cast(float, u);
}

// Kernel A: node MLP + projection to pa/pb (pair_b0 folded into pa).
__global__ __launch_bounds__(256) void node_kernel(
    const float* __restrict__ x,  const float* __restrict__ msk,
    const float* __restrict__ w0, const float* __restrict__ b0,
    const float* __restrict__ w1, const float* __restrict__ b1,
    const float* __restrict__ w2, const float* __restrict__ b2,
    const float* __restrict__ pw0,const float* __restrict__ pb0,
    float* __restrict__ pa, float* __restrict__ pb)
{
    int row = blockIdx.x*256 + threadIdx.x;
    if (row >= NROWS) return;

    float xr[FF];
    const float4* xp = reinterpret_cast<const float4*>(x + (size_t)row*FF);
#pragma unroll
    for (int q=0;q<FF/4;q++){ float4 v=xp[q]; xr[4*q]=v.x; xr[4*q+1]=v.y; xr[4*q+2]=v.z; xr[4*q+3]=v.w; }

    float h[HH];
#pragma unroll
    for (int k=0;k<HH;k++) h[k]=b0[k];
#pragma unroll
    for (int m=0;m<FF;m++){
        float xm = xr[m];
#pragma unroll
        for (int k=0;k<HH;k++) h[k] += xm * w0[m*HH+k];
    }
#pragma unroll
    for (int k=0;k<HH;k++) h[k]=elu_f(h[k]);

    float g[HH];
#pragma unroll
    for (int k=0;k<HH;k++) g[k]=b1[k];
#pragma unroll
    for (int m=0;m<HH;m++){
        float hm=h[m];
#pragma unroll
        for (int k=0;k<HH;k++) g[k] += hm * w1[m*HH+k];
    }
#pragma unroll
    for (int k=0;k<HH;k++) g[k]=elu_f(g[k]);

    float mk = msk[row];
    float npj[NO];
#pragma unroll
    for (int k=0;k<NO;k++) npj[k]=b2[k];
#pragma unroll
    for (int m=0;m<HH;m++){
        float gm=g[m];
#pragma unroll
        for (int k=0;k<NO;k++) npj[k] += gm * w2[m*NO+k];
    }
#pragma unroll
    for (int k=0;k<NO;k++) npj[k]=elu_f(npj[k])*mk;

    float pav[HH], pbv[HH];
#pragma unroll
    for (int k=0;k<HH;k++){ pav[k]=pb0[k]; pbv[k]=0.0f; }
#pragma unroll
    for (int m=0;m<NO;m++){
        float nm=npj[m];
#pragma unroll
        for (int k=0;k<HH;k++){
            pav[k] += nm * pw0[m*HH+k];
            pbv[k] += nm * pw0[(NO+m)*HH+k];
        }
    }
    float4* pap = reinterpret_cast<float4*>(pa + (size_t)row*HH);
    float4* pbp = reinterpret_cast<float4*>(pb + (size_t)row*HH);
#pragma unroll
    for (int q=0;q<HH/4;q++){
        pap[q]=make_float4(pav[4*q],pav[4*q+1],pav[4*q+2],pav[4*q+3]);
        pbp[q]=make_float4(pbv[4*q],pbv[4*q+1],pbv[4*q+2],pbv[4*q+3]);
    }
}

// ---- MFMA pair kernel ----
// Per block: one bnb, 16 consecutive i's. 256 threads = 4 waves.
// Per i: H0[j=128][k=32] = elu(pa_i + pb_j) (fp32, split to bf16 hi/lo in LDS,
// padded rows of 40 ushorts = 80 B for b128 alignment + even bank spread).
// Layer1: H1 = elu(H0 @ W1 + b1); Layer2: O = elu(elu-free...) via
// v_mfma_f32_16x16x32_bf16, 3 chained MFMA per tile (AloBhi+AhiBlo+AhiBhi).
// Wave w owns rows [32w,32w+32) end-to-end -> h0/h1 traffic is wave-local,
// only Os (output staging, contiguous 16KB tile) needs barriers (2 per i).
// Fragment layouts (16x16x32 bf16):
//   A: row m = lane&15, k = 8*(lane>>4)+{0..7}  (contiguous 8, one b128)
//   B: col n = lane&15, k = 8*(lane>>4)+{0..7}  (prepacked into regs)
//   C/D: col n = lane&15, row = 4*(lane>>4)+q   [HW-verified, m89]
#define SM_H0HI 0
#define SM_H0LO 10240
#define SM_H1HI 20480
#define SM_H1LO 30720
#define SM_OS   40960
#define SM_PAS  57344
#define SM_SIZE 59392

__global__ __launch_bounds__(256, 2) void pair_kernel(
    const float* __restrict__ pa, const float* __restrict__ pb,
    const float* __restrict__ pw1, const float* __restrict__ pb1,
    const float* __restrict__ pw2, const float* __restrict__ pb2,
    float* __restrict__ out)
{
    __shared__ __align__(16) char smem[SM_SIZE];
    ushort* h1hi = (ushort*)(smem + SM_H1HI);
    ushort* h1lo = (ushort*)(smem + SM_H1LO);
    float*  Os   = (float*) (smem + SM_OS);
    float*  pas  = (float*) (smem + SM_PAS);
    ushort* wf   = (ushort*)(smem + SM_H1HI);   // init-only, aliases h1

    const int t   = threadIdx.x;
    const int l   = t & 63;
    const int w   = t >> 6;
    const int bnb = blockIdx.x >> 3;
    const int ic  = blockIdx.x & 7;

    // ---- init: stage pa rows for this block's 16 i's (with pair_b0 folded)
    if (t < 128)
        ((f32x4*)pas)[t] = ((const f32x4*)(pa + ((size_t)bnb*PP + ic*16)*HH))[t];

    // ---- init: build bf16 hi/lo weight fragments in LDS (aliases h1)
    for (int ff = t; ff < 512; ff += 256){
        int L  = ff >> 8;
        int p  = (ff >> 7) & 1;
        int nt = (ff >> 6) & 1;
        int lf = ff & 63;
        const float* Wm = L ? pw2 : pw1;     // both 32x32 row-major [k][n]
        int n = nt*16 + (lf & 15);
#pragma unroll
        for (int jj = 0; jj < 8; jj++){
            int k = (lf >> 4)*8 + jj;
            float Wv = Wm[k*32 + n];
            unsigned short hb = bf16_hi(Wv);
            unsigned short v  = p ? bf16_hi(Wv - bf16_to_f(hb)) : hb;
            wf[ff*8 + jj] = v;
        }
    }
    __syncthreads();

    // ---- weight fragments + biases into registers
    s16x8 wfr[2][2][2];                       // [layer][part hi/lo][ntile]
#pragma unroll
    for (int L=0; L<2; L++)
#pragma unroll
    for (int p=0; p<2; p++)
#pragma unroll
    for (int nt=0; nt<2; nt++)
        wfr[L][p][nt] = *(const s16x8*)(wf + (((L*2+p)*2+nt)*64 + l)*8);

    float b1n[2], b2n[2];
    b1n[0] = pb1[t & 15];  b1n[1] = pb1[16 + (t & 15)];
    b2n[0] = pb2[t & 15];  b2n[1] = pb2[16 + (t & 15)];

    // ---- pb row in registers (thread t -> row j=t>>1, k-half kh=t&1)
    const int j  = t >> 1;
    const int kh = t & 1;
    float vbr[16];
    {
        const f32x4* q = (const f32x4*)(pb + ((size_t)bnb*PP + j)*HH + kh*16);
#pragma unroll
        for (int c=0;c<4;c++){
            f32x4 v = q[c];
            vbr[4*c]=v[0]; vbr[4*c+1]=v[1]; vbr[4*c+2]=v[2]; vbr[4*c+3]=v[3];
        }
    }
    __syncthreads();   // all wfr reads done before loop overwrites h1 region

    for (int i = 0; i < 16; i++){
        // ---- H0 form: h0[j][k] = elu(pa_i[k] + pb_j[k]), split hi/lo bf16
        {
            float pav[16];
            const f32x4* pp = (const f32x4*)(pas + i*32 + kh*16);
#pragma unroll
            for (int c=0;c<4;c++){
                f32x4 v = pp[c];
                pav[4*c]=v[0]; pav[4*c+1]=v[1]; pav[4*c+2]=v[2]; pav[4*c+3]=v[3];
            }
            unsigned hw[8], lw[8];
#pragma unroll
            for (int e=0;e<16;e++){
                float s = pav[e] + vbr[e];
                float f = elu_f(s);
                unsigned short hb = bf16_hi(f);
                unsigned short lb = bf16_hi(f - bf16_to_f(hb));
                if (e & 1){ hw[e>>1] |= ((unsigned)hb) << 16; lw[e>>1] |= ((unsigned)lb) << 16; }
                else      { hw[e>>1]  = hb;                   lw[e>>1]  = lb; }
            }
            size_t base = (size_t)j*80 + kh*32;
            u32x4 a0 = {hw[0],hw[1],hw[2],hw[3]}, a1 = {hw[4],hw[5],hw[6],hw[7]};
            u32x4 b0v = {lw[0],lw[1],lw[2],lw[3]}, b1v = {lw[4],lw[5],lw[6],lw[7]};
            *(u32x4*)(smem + SM_H0HI + base)      = a0;
            *(u32x4*)(smem + SM_H0HI + base + 16) = a1;
            *(u32x4*)(smem + SM_H0LO + base)      = b0v;
            *(u32x4*)(smem + SM_H0LO + base + 16) = b1v;
        }
        // wave-local RAW: wave w's H0 rows [32w,32w+32) are read only by wave w.

        // ---- Layer 1: H1 = elu(H0 @ W1 + b1)
        {
            s16x8 Ah[2], Al[2];
#pragma unroll
            for (int mt=0; mt<2; mt++){
                const char* ab = smem + SM_H0HI
                               + (size_t)(32*w + 16*mt + (l & 15))*80 + (l >> 4)*16;
                Ah[mt] = *(const s16x8*)ab;
                Al[mt] = *(const s16x8*)(ab + (SM_H0LO - SM_H0HI));
            }
            f32x4 acc[2][2];
#pragma unroll
            for (int mt=0; mt<2; mt++)
#pragma unroll
            for (int nt=0; nt<2; nt++){
                f32x4 c = {b1n[nt], b1n[nt], b1n[nt], b1n[nt]};
                c = __builtin_amdgcn_mfma_f32_16x16x32_bf16(Al[mt], wfr[0][0][nt], c, 0,0,0);
                c = __builtin_amdgcn_mfma_f32_16x16x32_bf16(Ah[mt], wfr[0][1][nt], c, 0,0,0);
                c = __builtin_amdgcn_mfma_f32_16x16x32_bf16(Ah[mt], wfr[0][0][nt], c, 0,0,0);
                acc[mt][nt] = c;
            }
#pragma unroll
            for (int mt=0; mt<2; mt++)
#pragma unroll
            for (int nt=0; nt<2; nt++)
#pragma unroll
            for (int q=0; q<4; q++){
                int jrow = 32*w + 16*mt + 4*(l >> 4) + q;
                int n    = 16*nt + (l & 15);
                float e  = elu_f(acc[mt][nt][q]);
                unsigned short hb = bf16_hi(e);
                unsigned short lb = bf16_hi(e - bf16_to_f(hb));
                h1hi[jrow*40 + n] = hb;
                h1lo[jrow*40 + n] = lb;
            }
        }
        // wave-local RAW again (h1 rows [32w,32w+32) produced & consumed by wave w).

        // ---- Layer 2: O = elu(H1 @ W2 + b2) -> Os (fp32, global tile layout)
        {
            s16x8 Ah[2], Al[2];
#pragma unroll
            for (int mt=0; mt<2; mt++){
                const char* ab = smem + SM_H1HI
                               + (size_t)(32*w + 16*mt + (l & 15))*80 + (l >> 4)*16;
                Ah[mt] = *(const s16x8*)ab;
                Al[mt] = *(const s16x8*)(ab + (SM_H1LO - SM_H1HI));
            }
#pragma unroll
            for (int mt=0; mt<2; mt++)
#pragma unroll
            for (int nt=0; nt<2; nt++){
                f32x4 c = {b2n[nt], b2n[nt], b2n[nt], b2n[nt]};
                c = __builtin_amdgcn_mfma_f32_16x16x32_bf16(Al[mt], wfr[1][0][nt], c, 0,0,0);
                c = __builtin_amdgcn_mfma_f32_16x16x32_bf16(Ah[mt], wfr[1][1][nt], c, 0,0,0);
                c = __builtin_amdgcn_mfma_f32_16x16x32_bf16(Ah[mt], wfr[1][0][nt], c, 0,0,0);
#pragma unroll
                for (int q=0; q<4; q++){
                    int jrow = 32*w + 16*mt + 4*(l >> 4) + q;
                    int n    = 16*nt + (l & 15);
                    Os[jrow*32 + n] = elu_f(c[q]);
                }
            }
        }
        __syncthreads();   // Os complete (cross-wave read next)

        // ---- coalesced writeout: contiguous 16 KB tile
        {
            f32x4* dst = (f32x4*)(out + ((size_t)(bnb*PP + ic*16 + i))*PP*OUTC);
            const f32x4* src = (const f32x4*)Os;
#pragma unroll
            for (int r=0; r<4; r++)
                dst[t + 256*r] = src[t + 256*r];
        }
        __syncthreads();   // Os free for next i
    }
}

extern "C" void kernel_launch(void* const* d_in, const int* in_sizes, int n_in,
                              void* d_out, int out_size, void* d_ws, size_t ws_size,
                              hipStream_t stream) {
    const float* x    = (const float*)d_in[0];
    const float* msk  = (const float*)d_in[1];
    const float* nw0  = (const float*)d_in[2];
    const float* nb0  = (const float*)d_in[3];
    const float* nw1  = (const float*)d_in[4];
    const float* nb1  = (const float*)d_in[5];
    const float* nw2  = (const float*)d_in[6];
    const float* nb2  = (const float*)d_in[7];
    const float* pw0  = (const float*)d_in[8];
    const float* pb0  = (const float*)d_in[9];
    const float* pw1  = (const float*)d_in[10];
    const float* pb1  = (const float*)d_in[11];
    const float* pw2  = (const float*)d_in[12];
    const float* pb2  = (const float*)d_in[13];
    float* out = (float*)d_out;

    float* pa = (float*)d_ws;                       // 8192*32 floats = 1 MiB
    float* pb = pa + (size_t)NROWS*HH;              // +1 MiB

    node_kernel<<<NROWS/256, 256, 0, stream>>>(x, msk, nw0, nb0, nw1, nb1,
                                               nw2, nb2, pw0, pb0, pa, pb);
    pair_kernel<<<BB*NBB*8, 256, 0, stream>>>(pa, pb, pw1, pb1,
                                              pw2, pb2, out);
}

// Round 7
// 84.449 us; speedup vs baseline: 8.6707x; 1.0838x over previous
//
#include <hip/hip_runtime.h>

// Problem dims (fixed by reference)
#define BB   2
#define NBB  32
#define PP   128
#define FF   32
#define HH   32
#define NO   8
#define OUTC 32
#define NROWS (BB*NBB*PP)   // 8192

typedef float  f32x4 __attribute__((ext_vector_type(4)));
typedef short  s16x8 __attribute__((ext_vector_type(8)));
typedef unsigned int u32x2 __attribute__((ext_vector_type(2)));

__device__ __forceinline__ float elu_f(float x){
    return x > 0.0f ? x : (__expf(x) - 1.0f);
}
// round-to-nearest-even fp32 -> bf16 bits
__device__ __forceinline__ unsigned short bf16_hi(float f){
    unsigned u = __builtin_bit_cast(unsigned, f);
    unsigned r = u + 0x7FFFu + ((u >> 16) & 1u);
    return (unsigned short)(r >> 16);
}
__device__ __forceinline__ float bf16_to_f(unsigned short h){
    unsigned u = ((unsigned)h) << 16;
    return __builtin_bit_cast(float, u);
}

// Kernel A: node MLP + projection to pa/pb (pair_b0 folded into pa).
__global__ __launch_bounds__(256) void node_kernel(
    const float* __restrict__ x,  const float* __restrict__ msk,
    const float* __restrict__ w0, const float* __restrict__ b0,
    const float* __restrict__ w1, const float* __restrict__ b1,
    const float* __restrict__ w2, const float* __restrict__ b2,
    const float* __restrict__ pw0,const float* __restrict__ pb0,
    float* __restrict__ pa, float* __restrict__ pb)
{
    int row = blockIdx.x*256 + threadIdx.x;
    if (row >= NROWS) return;

    float xr[FF];
    const float4* xp = reinterpret_cast<const float4*>(x + (size_t)row*FF);
#pragma unroll
    for (int q=0;q<FF/4;q++){ float4 v=xp[q]; xr[4*q]=v.x; xr[4*q+1]=v.y; xr[4*q+2]=v.z; xr[4*q+3]=v.w; }

    float h[HH];
#pragma unroll
    for (int k=0;k<HH;k++) h[k]=b0[k];
#pragma unroll
    for (int m=0;m<FF;m++){
        float xm = xr[m];
#pragma unroll
        for (int k=0;k<HH;k++) h[k] += xm * w0[m*HH+k];
    }
#pragma unroll
    for (int k=0;k<HH;k++) h[k]=elu_f(h[k]);

    float g[HH];
#pragma unroll
    for (int k=0;k<HH;k++) g[k]=b1[k];
#pragma unroll
    for (int m=0;m<HH;m++){
        float hm=h[m];
#pragma unroll
        for (int k=0;k<HH;k++) g[k] += hm * w1[m*HH+k];
    }
#pragma unroll
    for (int k=0;k<HH;k++) g[k]=elu_f(g[k]);

    float mk = msk[row];
    float npj[NO];
#pragma unroll
    for (int k=0;k<NO;k++) npj[k]=b2[k];
#pragma unroll
    for (int m=0;m<HH;m++){
        float gm=g[m];
#pragma unroll
        for (int k=0;k<NO;k++) npj[k] += gm * w2[m*NO+k];
    }
#pragma unroll
    for (int k=0;k<NO;k++) npj[k]=elu_f(npj[k])*mk;

    float pav[HH], pbv[HH];
#pragma unroll
    for (int k=0;k<HH;k++){ pav[k]=pb0[k]; pbv[k]=0.0f; }
#pragma unroll
    for (int m=0;m<NO;m++){
        float nm=npj[m];
#pragma unroll
        for (int k=0;k<HH;k++){
            pav[k] += nm * pw0[m*HH+k];
            pbv[k] += nm * pw0[(NO+m)*HH+k];
        }
    }
    float4* pap = reinterpret_cast<float4*>(pa + (size_t)row*HH);
    float4* pbp = reinterpret_cast<float4*>(pb + (size_t)row*HH);
#pragma unroll
    for (int q=0;q<HH/4;q++){
        pap[q]=make_float4(pav[4*q],pav[4*q+1],pav[4*q+2],pav[4*q+3]);
        pbp[q]=make_float4(pbv[4*q],pbv[4*q+1],pbv[4*q+2],pbv[4*q+3]);
    }
}

// ---- Transposed-MFMA pair kernel ----
// All GEMMs computed transposed: H1^T = W1^T @ H0^T, O^T = W2^T @ H1^T via
// mfma_f32_16x16x32_bf16 (A = W^T in regs; B = activations^T).
//   A frag: row m=l&15(+16mt), k=8h+{0..7}
//   B frag: col n=pair j=l&15(+16jt), k=8h+{0..7}
//   D frag: col n=pair j=l&15, row m=feature 4h+q(+16mt)   [HW-verified]
// H0^T is generated per-lane directly as B fragments (NO LDS round-trip).
// L1->L2 handoff: vector ds_write_b64 x8 + ds_read_b128 x4, wave-local rows
// (each wave owns pairs [32w,32w+32)) -> no barrier needed.
// Os staged with XOR swizzle (slot ^= j&7), double-buffered -> 1 barrier/i,
// writeout is contiguous 4 KB/instruction (clean-write path from R5).
#define SM_PAS  0        // 2048 B
#define SM_H1HI 2048     // 128 rows * 80 B = 10240
#define SM_H1LO 12288    // 10240
#define SM_OS   22528    // 2 * 16384
#define SM_SIZE 55296

__global__ __launch_bounds__(256, 2) void pair_kernel(
    const float* __restrict__ pa, const float* __restrict__ pb,
    const float* __restrict__ pw1, const float* __restrict__ pb1,
    const float* __restrict__ pw2, const float* __restrict__ pb2,
    float* __restrict__ out)
{
    __shared__ __align__(16) char smem[SM_SIZE];
    float* pas  = (float*)(smem + SM_PAS);
    char*  h1hi = smem + SM_H1HI;
    char*  h1lo = smem + SM_H1LO;

    const int t   = threadIdx.x;
    const int l   = t & 63;
    const int w   = t >> 6;
    const int h   = l >> 4;
    const int ln  = l & 15;
    const int bnb = blockIdx.x >> 3;
    const int ic  = blockIdx.x & 7;

    // ---- stage pa rows for this block's 16 i's (pair_b0 folded)
    if (t < 128)
        ((f32x4*)pas)[t] = ((const f32x4*)(pa + ((size_t)bnb*PP + ic*16)*HH))[t];

    // ---- W^T A-fragments in registers (strided global scalar loads, L2-hot)
    s16x8 wfr[2][2][2];   // [layer][0=hi,1=lo][mt]
#pragma unroll
    for (int L=0; L<2; L++){
        const float* W = L ? pw2 : pw1;   // 32x32 row-major [k][n]
#pragma unroll
        for (int mt=0; mt<2; mt++){
            unsigned short hb8[8], lb8[8];
#pragma unroll
            for (int e=0; e<8; e++){
                float v = W[(8*h+e)*32 + 16*mt + ln];   // W^T[m][k] = W[k][m]
                unsigned short hb = bf16_hi(v);
                hb8[e] = hb;
                lb8[e] = bf16_hi(v - bf16_to_f(hb));
            }
            s16x8 th, tl;
#pragma unroll
            for (int e=0; e<8; e++){ th[e]=(short)hb8[e]; tl[e]=(short)lb8[e]; }
            wfr[L][0][mt] = th;  wfr[L][1][mt] = tl;
        }
    }

    // ---- biases as D-fragment f32x4 (feature = 16mt+4h+q)
    f32x4 b1v[2], b2v[2];
#pragma unroll
    for (int mt=0; mt<2; mt++){
        b1v[mt] = *(const f32x4*)(pb1 + 16*mt + 4*h);
        b2v[mt] = *(const f32x4*)(pb2 + 16*mt + 4*h);
    }

    // ---- pb slices (lane's B-frag k-slice for its 2 pair-tiles), hoisted
    float pbr[2][8];
#pragma unroll
    for (int jj=0; jj<2; jj++){
        const float* q = pb + ((size_t)bnb*PP + 32*w + 16*jj + ln)*HH + 8*h;
        f32x4 v0 = *(const f32x4*)q, v1 = *(const f32x4*)(q+4);
#pragma unroll
        for (int c=0;c<4;c++){ pbr[jj][c]=v0[c]; pbr[jj][4+c]=v1[c]; }
    }
    __syncthreads();

#pragma unroll 2
    for (int i = 0; i < 16; i++){
        float* Osb = (float*)(smem + SM_OS + (i&1)*16384);

        // ---- H0^T B-fragments straight into registers
        float par[8];
        {
            const f32x4* pp = (const f32x4*)(pas + i*32 + 8*h);
            f32x4 v0 = pp[0], v1 = pp[1];
#pragma unroll
            for (int c=0;c<4;c++){ par[c]=v0[c]; par[4+c]=v1[c]; }
        }
        s16x8 bh[2], bl[2];
#pragma unroll
        for (int jj=0; jj<2; jj++){
            s16x8 th, tl;
#pragma unroll
            for (int e=0; e<8; e++){
                float f = elu_f(par[e] + pbr[jj][e]);
                unsigned short hb = bf16_hi(f);
                th[e] = (short)hb;
                tl[e] = (short)bf16_hi(f - bf16_to_f(hb));
            }
            bh[jj]=th; bl[jj]=tl;
        }

        // ---- Layer 1: H1^T = W1^T @ H0^T  (3-MFMA hi/lo chain)
        f32x4 acc[2][2];
#pragma unroll
        for (int mt=0; mt<2; mt++)
#pragma unroll
        for (int jj=0; jj<2; jj++){
            f32x4 c = b1v[mt];
            c = __builtin_amdgcn_mfma_f32_16x16x32_bf16(wfr[0][1][mt], bh[jj], c, 0,0,0);
            c = __builtin_amdgcn_mfma_f32_16x16x32_bf16(wfr[0][0][mt], bl[jj], c, 0,0,0);
            c = __builtin_amdgcn_mfma_f32_16x16x32_bf16(wfr[0][0][mt], bh[jj], c, 0,0,0);
            acc[mt][jj] = c;
        }

        // ---- epilogue -> h1 LDS (vector b64 writes, wave-local rows)
#pragma unroll
        for (int mt=0; mt<2; mt++)
#pragma unroll
        for (int jj=0; jj<2; jj++){
            int j = 32*w + 16*jj + ln;
            unsigned hw_[2], lw_[2];
#pragma unroll
            for (int q=0; q<4; q++){
                float e = elu_f(acc[mt][jj][q]);
                unsigned short hb = bf16_hi(e);
                unsigned short lb = bf16_hi(e - bf16_to_f(hb));
                if (q & 1){ hw_[q>>1] |= ((unsigned)hb)<<16; lw_[q>>1] |= ((unsigned)lb)<<16; }
                else      { hw_[q>>1]  = hb;                 lw_[q>>1]  = lb; }
            }
            size_t off = (size_t)j*80 + 32*mt + 8*h;
            *(u32x2*)(h1hi + off) = u32x2{hw_[0], hw_[1]};
            *(u32x2*)(h1lo + off) = u32x2{lw_[0], lw_[1]};
        }
        // wave-local RAW (each wave reads only its own pairs) -> no barrier

        // ---- Layer 2 B-fragments (vector b128 reads)
        s16x8 c2h[2], c2l[2];
#pragma unroll
        for (int jj=0; jj<2; jj++){
            size_t off = (size_t)(32*w + 16*jj + ln)*80 + 16*h;
            c2h[jj] = *(const s16x8*)(h1hi + off);
            c2l[jj] = *(const s16x8*)(h1lo + off);
        }

        // ---- Layer 2: O^T = W2^T @ H1^T -> Os (swizzled b128 writes)
#pragma unroll
        for (int mt=0; mt<2; mt++)
#pragma unroll
        for (int jj=0; jj<2; jj++){
            f32x4 c = b2v[mt];
            c = __builtin_amdgcn_mfma_f32_16x16x32_bf16(wfr[1][1][mt], c2h[jj], c, 0,0,0);
            c = __builtin_amdgcn_mfma_f32_16x16x32_bf16(wfr[1][0][mt], c2l[jj], c, 0,0,0);
            c = __builtin_amdgcn_mfma_f32_16x16x32_bf16(wfr[1][0][mt], c2h[jj], c, 0,0,0);
            f32x4 o;
#pragma unroll
            for (int q=0; q<4; q++) o[q] = elu_f(c[q]);
            int j = 32*w + 16*jj + ln;
            int slot = (4*mt + h) ^ (j & 7);
            *(f32x4*)((char*)Osb + j*128 + slot*16) = o;
        }
        __syncthreads();   // Os tile complete (cross-wave writeout next)

        // ---- coalesced writeout: contiguous 4 KB per instruction
        {
            f32x4* dst = (f32x4*)(out + ((size_t)(bnb*PP + ic*16 + i))*PP*OUTC);
#pragma unroll
            for (int r=0; r<4; r++){
                int L = t + 256*r;
                int j = L >> 3, s = (L & 7) ^ (j & 7);
                dst[L] = *(const f32x4*)((const char*)Osb + j*128 + s*16);
            }
        }
        // no second barrier: next i writes the other Os buffer; any wave
        // re-entering this buffer must first pass the NEXT barrier.
    }
}

extern "C" void kernel_launch(void* const* d_in, const int* in_sizes, int n_in,
                              void* d_out, int out_size, void* d_ws, size_t ws_size,
                              hipStream_t stream) {
    const float* x    = (const float*)d_in[0];
    const float* msk  = (const float*)d_in[1];
    const float* nw0  = (const float*)d_in[2];
    const float* nb0  = (const float*)d_in[3];
    const float* nw1  = (const float*)d_in[4];
    const float* nb1  = (const float*)d_in[5];
    const float* nw2  = (const float*)d_in[6];
    const float* nb2  = (const float*)d_in[7];
    const float* pw0  = (const float*)d_in[8];
    const float* pb0  = (const float*)d_in[9];
    const float* pw1  = (const float*)d_in[10];
    const float* pb1  = (const float*)d_in[11];
    const float* pw2  = (const float*)d_in[12];
    const float* pb2  = (const float*)d_in[13];
    float* out = (float*)d_out;

    float* pa = (float*)d_ws;                       // 8192*32 floats = 1 MiB
    float* pb = pa + (size_t)NROWS*HH;              // +1 MiB

    node_kernel<<<NROWS/256, 256, 0, stream>>>(x, msk, nw0, nb0, nw1, nb1,
                                               nw2, nb2, pw0, pb0, pa, pb);
    pair_kernel<<<BB*NBB*8, 256, 0, stream>>>(pa, pb, pw1, pb1,
                                              pw2, pb2, out);
}

// Round 8
// 71.772 us; speedup vs baseline: 10.2022x; 1.1766x over previous
//
#include <hip/hip_runtime.h>

// Problem dims (fixed by reference)
#define BB   2
#define NBB  32
#define PP   128
#define FF   32
#define HH   32
#define NO   8
#define OUTC 32
#define NROWS (BB*NBB*PP)   // 8192

typedef float    f32x4 __attribute__((ext_vector_type(4)));
typedef _Float16 f16x8 __attribute__((ext_vector_type(8)));
typedef _Float16 f16x4 __attribute__((ext_vector_type(4)));

__device__ __forceinline__ float elu_f(float x){
    return x > 0.0f ? x : (__expf(x) - 1.0f);
}

// Kernel A: node MLP + projection to pa/pb (pair_b0 folded into pa).
__global__ __launch_bounds__(256) void node_kernel(
    const float* __restrict__ x,  const float* __restrict__ msk,
    const float* __restrict__ w0, const float* __restrict__ b0,
    const float* __restrict__ w1, const float* __restrict__ b1,
    const float* __restrict__ w2, const float* __restrict__ b2,
    const float* __restrict__ pw0,const float* __restrict__ pb0,
    float* __restrict__ pa, float* __restrict__ pb)
{
    int row = blockIdx.x*256 + threadIdx.x;
    if (row >= NROWS) return;

    float xr[FF];
    const float4* xp = reinterpret_cast<const float4*>(x + (size_t)row*FF);
#pragma unroll
    for (int q=0;q<FF/4;q++){ float4 v=xp[q]; xr[4*q]=v.x; xr[4*q+1]=v.y; xr[4*q+2]=v.z; xr[4*q+3]=v.w; }

    float h[HH];
#pragma unroll
    for (int k=0;k<HH;k++) h[k]=b0[k];
#pragma unroll
    for (int m=0;m<FF;m++){
        float xm = xr[m];
#pragma unroll
        for (int k=0;k<HH;k++) h[k] += xm * w0[m*HH+k];
    }
#pragma unroll
    for (int k=0;k<HH;k++) h[k]=elu_f(h[k]);

    float g[HH];
#pragma unroll
    for (int k=0;k<HH;k++) g[k]=b1[k];
#pragma unroll
    for (int m=0;m<HH;m++){
        float hm=h[m];
#pragma unroll
        for (int k=0;k<HH;k++) g[k] += hm * w1[m*HH+k];
    }
#pragma unroll
    for (int k=0;k<HH;k++) g[k]=elu_f(g[k]);

    float mk = msk[row];
    float npj[NO];
#pragma unroll
    for (int k=0;k<NO;k++) npj[k]=b2[k];
#pragma unroll
    for (int m=0;m<HH;m++){
        float gm=g[m];
#pragma unroll
        for (int k=0;k<NO;k++) npj[k] += gm * w2[m*NO+k];
    }
#pragma unroll
    for (int k=0;k<NO;k++) npj[k]=elu_f(npj[k])*mk;

    float pav[HH], pbv[HH];
#pragma unroll
    for (int k=0;k<HH;k++){ pav[k]=pb0[k]; pbv[k]=0.0f; }
#pragma unroll
    for (int m=0;m<NO;m++){
        float nm=npj[m];
#pragma unroll
        for (int k=0;k<HH;k++){
            pav[k] += nm * pw0[m*HH+k];
            pbv[k] += nm * pw0[(NO+m)*HH+k];
        }
    }
    float4* pap = reinterpret_cast<float4*>(pa + (size_t)row*HH);
    float4* pbp = reinterpret_cast<float4*>(pb + (size_t)row*HH);
#pragma unroll
    for (int q=0;q<HH/4;q++){
        pap[q]=make_float4(pav[4*q],pav[4*q+1],pav[4*q+2],pav[4*q+3]);
        pbp[q]=make_float4(pbv[4*q],pbv[4*q+1],pbv[4*q+2],pbv[4*q+3]);
    }
}

// ---- Transposed-MFMA pair kernel, fp16 single-MFMA ----
// All GEMMs computed transposed: H1^T = W1^T @ H0^T, O^T = W2^T @ H1^T via
// mfma_f32_16x16x32_f16 (A = W^T in regs; B = activations^T, fp16).
//   A frag: row m=ln(+16mt), k=8h+{0..7}
//   B frag: col n=pair j=ln(+16jj), k=8h+{0..7}
//   D frag: col n=pair j=ln, row m=feature 4h+q(+16mt)   [HW-verified]
// fp16 (2^-11 rel) replaces R7's bf16 hi/lo 3-chain: 24->8 MFMA/thread/i,
// no split machinery (~18->7 VALU ops/elem). LDS 55->44 KB -> 3 blocks/CU.
// H0^T generated per-lane directly as B fragments (no LDS round-trip).
// L1->L2 handoff: ds_write_b64 + ds_read_b128, wave-local rows, 80 B row
// stride (16-aligned, <=2-way bank aliasing = free). 1 barrier per i.
#define SM_PAS  0        // 2048 B
#define SM_H1   2048     // 128 rows * 80 B = 10240
#define SM_OS   12288    // 2 * 16384
#define SM_SIZE 45056

__global__ __launch_bounds__(256, 3) void pair_kernel(
    const float* __restrict__ pa, const float* __restrict__ pb,
    const float* __restrict__ pw1, const float* __restrict__ pb1,
    const float* __restrict__ pw2, const float* __restrict__ pb2,
    float* __restrict__ out)
{
    __shared__ __align__(16) char smem[SM_SIZE];
    float* pas = (float*)(smem + SM_PAS);
    char*  h1  = smem + SM_H1;

    const int t   = threadIdx.x;
    const int l   = t & 63;
    const int w   = t >> 6;
    const int h   = l >> 4;
    const int ln  = l & 15;
    const int bnb = blockIdx.x >> 3;
    const int ic  = blockIdx.x & 7;

    // ---- stage pa rows for this block's 16 i's (pair_b0 folded)
    if (t < 128)
        ((f32x4*)pas)[t] = ((const f32x4*)(pa + ((size_t)bnb*PP + ic*16)*HH))[t];

    // ---- W^T A-fragments in registers (strided global loads, L2-hot)
    f16x8 wfr[2][2];   // [layer][mt]
#pragma unroll
    for (int L=0; L<2; L++){
        const float* W = L ? pw2 : pw1;   // 32x32 row-major [k][n]
#pragma unroll
        for (int mt=0; mt<2; mt++){
            f16x8 a;
#pragma unroll
            for (int e=0; e<8; e++)
                a[e] = (_Float16)W[(8*h+e)*32 + 16*mt + ln];  // W^T[m][k]=W[k][m]
            wfr[L][mt] = a;
        }
    }

    // ---- biases as D-fragment f32x4 (feature = 16mt+4h+q)
    f32x4 b1v[2], b2v[2];
#pragma unroll
    for (int mt=0; mt<2; mt++){
        b1v[mt] = *(const f32x4*)(pb1 + 16*mt + 4*h);
        b2v[mt] = *(const f32x4*)(pb2 + 16*mt + 4*h);
    }

    // ---- pb slices (lane's B-frag k-slice for its 2 pair-tiles), hoisted
    float pbr[2][8];
#pragma unroll
    for (int jj=0; jj<2; jj++){
        const float* q = pb + ((size_t)bnb*PP + 32*w + 16*jj + ln)*HH + 8*h;
        f32x4 v0 = *(const f32x4*)q, v1 = *(const f32x4*)(q+4);
#pragma unroll
        for (int c=0;c<4;c++){ pbr[jj][c]=v0[c]; pbr[jj][4+c]=v1[c]; }
    }
    __syncthreads();

#pragma unroll 2
    for (int i = 0; i < 16; i++){
        float* Osb = (float*)(smem + SM_OS + (i&1)*16384);

        // ---- H0^T B-fragments straight into registers (fp16)
        float par[8];
        {
            const f32x4* pp = (const f32x4*)(pas + i*32 + 8*h);
            f32x4 v0 = pp[0], v1 = pp[1];
#pragma unroll
            for (int c=0;c<4;c++){ par[c]=v0[c]; par[4+c]=v1[c]; }
        }
        f16x8 bh[2];
#pragma unroll
        for (int jj=0; jj<2; jj++){
            f16x8 b;
#pragma unroll
            for (int e=0; e<8; e++)
                b[e] = (_Float16)elu_f(par[e] + pbr[jj][e]);
            bh[jj] = b;
        }

        // ---- Layer 1: H1^T = W1^T @ H0^T
        f32x4 acc[2][2];
#pragma unroll
        for (int mt=0; mt<2; mt++)
#pragma unroll
        for (int jj=0; jj<2; jj++)
            acc[mt][jj] = __builtin_amdgcn_mfma_f32_16x16x32_f16(
                              wfr[0][mt], bh[jj], b1v[mt], 0,0,0);

        // ---- epilogue -> h1 LDS (b64 writes, wave-local rows, stride 80 B)
#pragma unroll
        for (int mt=0; mt<2; mt++)
#pragma unroll
        for (int jj=0; jj<2; jj++){
            int j = 32*w + 16*jj + ln;
            f16x4 p;
#pragma unroll
            for (int q=0; q<4; q++) p[q] = (_Float16)elu_f(acc[mt][jj][q]);
            *(f16x4*)(h1 + (size_t)j*80 + 32*mt + 8*h) = p;
        }
        // wave-local RAW (each wave reads only its own pairs) -> no barrier

        // ---- Layer 2 B-fragments (b128 reads, features 8h..8h+7)
        f16x8 c2[2];
#pragma unroll
        for (int jj=0; jj<2; jj++)
            c2[jj] = *(const f16x8*)(h1 + (size_t)(32*w + 16*jj + ln)*80 + 16*h);

        // ---- Layer 2: O^T = W2^T @ H1^T -> Os (swizzled b128 writes)
#pragma unroll
        for (int mt=0; mt<2; mt++)
#pragma unroll
        for (int jj=0; jj<2; jj++){
            f32x4 c = __builtin_amdgcn_mfma_f32_16x16x32_f16(
                          wfr[1][mt], c2[jj], b2v[mt], 0,0,0);
            f32x4 o;
#pragma unroll
            for (int q=0; q<4; q++) o[q] = elu_f(c[q]);
            int j = 32*w + 16*jj + ln;
            int slot = (4*mt + h) ^ (j & 7);
            *(f32x4*)((char*)Osb + j*128 + slot*16) = o;
        }
        __syncthreads();   // Os tile complete (cross-wave writeout next)

        // ---- coalesced writeout: contiguous 4 KB per instruction
        {
            f32x4* dst = (f32x4*)(out + ((size_t)(bnb*PP + ic*16 + i))*PP*OUTC);
#pragma unroll
            for (int r=0; r<4; r++){
                int L = t + 256*r;
                int j = L >> 3, s = (L & 7) ^ (j & 7);
                dst[L] = *(const f32x4*)((const char*)Osb + j*128 + s*16);
            }
        }
        // no second barrier: next i writes the other Os buffer; any wave
        // re-entering this buffer must first pass the NEXT barrier.
    }
}

extern "C" void kernel_launch(void* const* d_in, const int* in_sizes, int n_in,
                              void* d_out, int out_size, void* d_ws, size_t ws_size,
                              hipStream_t stream) {
    const float* x    = (const float*)d_in[0];
    const float* msk  = (const float*)d_in[1];
    const float* nw0  = (const float*)d_in[2];
    const float* nb0  = (const float*)d_in[3];
    const float* nw1  = (const float*)d_in[4];
    const float* nb1  = (const float*)d_in[5];
    const float* nw2  = (const float*)d_in[6];
    const float* nb2  = (const float*)d_in[7];
    const float* pw0  = (const float*)d_in[8];
    const float* pb0  = (const float*)d_in[9];
    const float* pw1  = (const float*)d_in[10];
    const float* pb1  = (const float*)d_in[11];
    const float* pw2  = (const float*)d_in[12];
    const float* pb2  = (const float*)d_in[13];
    float* out = (float*)d_out;

    float* pa = (float*)d_ws;                       // 8192*32 floats = 1 MiB
    float* pb = pa + (size_t)NROWS*HH;              // +1 MiB

    node_kernel<<<NROWS/256, 256, 0, stream>>>(x, msk, nw0, nb0, nw1, nb1,
                                               nw2, nb2, pw0, pb0, pa, pb);
    pair_kernel<<<BB*NBB*8, 256, 0, stream>>>(pa, pb, pw1, pb1,
                                              pw2, pb2, out);
}

// Round 9
// 66.008 us; speedup vs baseline: 11.0931x; 1.0873x over previous
//
#include <hip/hip_runtime.h>

// Problem dims (fixed by reference)
#define BB   2
#define NBB  32
#define PP   128
#define FF   32
#define HH   32
#define NO   8
#define OUTC 32
#define NROWS (BB*NBB*PP)   // 8192

typedef float    f32x4 __attribute__((ext_vector_type(4)));
typedef _Float16 f16x8 __attribute__((ext_vector_type(8)));
typedef _Float16 f16x4 __attribute__((ext_vector_type(4)));

__device__ __forceinline__ float elu_f(float x){
    return x > 0.0f ? x : (__expf(x) - 1.0f);
}

// Kernel A: node MLP + projection to pa/pb (pair_b0 folded into pa).
__global__ __launch_bounds__(256) void node_kernel(
    const float* __restrict__ x,  const float* __restrict__ msk,
    const float* __restrict__ w0, const float* __restrict__ b0,
    const float* __restrict__ w1, const float* __restrict__ b1,
    const float* __restrict__ w2, const float* __restrict__ b2,
    const float* __restrict__ pw0,const float* __restrict__ pb0,
    float* __restrict__ pa, float* __restrict__ pb)
{
    int row = blockIdx.x*256 + threadIdx.x;
    if (row >= NROWS) return;

    float xr[FF];
    const float4* xp = reinterpret_cast<const float4*>(x + (size_t)row*FF);
#pragma unroll
    for (int q=0;q<FF/4;q++){ float4 v=xp[q]; xr[4*q]=v.x; xr[4*q+1]=v.y; xr[4*q+2]=v.z; xr[4*q+3]=v.w; }

    float h[HH];
#pragma unroll
    for (int k=0;k<HH;k++) h[k]=b0[k];
#pragma unroll
    for (int m=0;m<FF;m++){
        float xm = xr[m];
#pragma unroll
        for (int k=0;k<HH;k++) h[k] += xm * w0[m*HH+k];
    }
#pragma unroll
    for (int k=0;k<HH;k++) h[k]=elu_f(h[k]);

    float g[HH];
#pragma unroll
    for (int k=0;k<HH;k++) g[k]=b1[k];
#pragma unroll
    for (int m=0;m<HH;m++){
        float hm=h[m];
#pragma unroll
        for (int k=0;k<HH;k++) g[k] += hm * w1[m*HH+k];
    }
#pragma unroll
    for (int k=0;k<HH;k++) g[k]=elu_f(g[k]);

    float mk = msk[row];
    float npj[NO];
#pragma unroll
    for (int k=0;k<NO;k++) npj[k]=b2[k];
#pragma unroll
    for (int m=0;m<HH;m++){
        float gm=g[m];
#pragma unroll
        for (int k=0;k<NO;k++) npj[k] += gm * w2[m*NO+k];
    }
#pragma unroll
    for (int k=0;k<NO;k++) npj[k]=elu_f(npj[k])*mk;

    float pav[HH], pbv[HH];
#pragma unroll
    for (int k=0;k<HH;k++){ pav[k]=pb0[k]; pbv[k]=0.0f; }
#pragma unroll
    for (int m=0;m<NO;m++){
        float nm=npj[m];
#pragma unroll
        for (int k=0;k<HH;k++){
            pav[k] += nm * pw0[m*HH+k];
            pbv[k] += nm * pw0[(NO+m)*HH+k];
        }
    }
    float4* pap = reinterpret_cast<float4*>(pa + (size_t)row*HH);
    float4* pbp = reinterpret_cast<float4*>(pb + (size_t)row*HH);
#pragma unroll
    for (int q=0;q<HH/4;q++){
        pap[q]=make_float4(pav[4*q],pav[4*q+1],pav[4*q+2],pav[4*q+3]);
        pbp[q]=make_float4(pbv[4*q],pbv[4*q+1],pbv[4*q+2],pbv[4*q+3]);
    }
}

// ---- Transposed-MFMA pair kernel, fp16, direct D-fragment stores ----
// GEMMs transposed: H1^T = W1^T @ H0^T, O^T = W2^T @ H1^T (mfma 16x16x32_f16).
//   A frag: row m=ln(+16mt), k=8h+{0..7}
//   B frag: col n=pair j=ln(+16jj), k=8h+{0..7}
//   D frag: col n=pair j=ln, row m=feature 16mt+4h+{0..3}  (contiguous x4!)
// KEY (R8->R9): the D fragment is stored DIRECTLY to global. One wave store
// (fixed mt,jj) = 16 rows x contiguous 64 B (h=0..3) = full sectors, so no
// partial-line RMW (R3/R4's killer was 16 B granularity). mt=0/mt=1 halves
// of each 128 B line issue back-to-back (jj outer, mt inner) for L2 merge.
// This deletes the Os LDS tile, the per-i barrier (and its implicit
// s_waitcnt vmcnt(0) drain), and 8 DS ops/thread/i. LDS 45->12.3 KB.
// Grid: 8 i's per block -> 1024 blocks = 4 blocks/CU (16 waves/CU).
#define SM_PAS  0        // 8 rows * 32 f32 = 1024 B
#define SM_H1   1024     // 128 rows * 80 B = 10240
#define SM_SIZE 11264

__global__ __launch_bounds__(256, 4) void pair_kernel(
    const float* __restrict__ pa, const float* __restrict__ pb,
    const float* __restrict__ pw1, const float* __restrict__ pb1,
    const float* __restrict__ pw2, const float* __restrict__ pb2,
    float* __restrict__ out)
{
    __shared__ __align__(16) char smem[SM_SIZE];
    float* pas = (float*)(smem + SM_PAS);
    char*  h1  = smem + SM_H1;

    const int t   = threadIdx.x;
    const int l   = t & 63;
    const int w   = t >> 6;
    const int h   = l >> 4;
    const int ln  = l & 15;
    const int bnb = blockIdx.x >> 4;
    const int ic  = blockIdx.x & 15;

    // ---- stage pa rows for this block's 8 i's (pair_b0 folded)
    if (t < 64)
        ((f32x4*)pas)[t] = ((const f32x4*)(pa + ((size_t)bnb*PP + ic*8)*HH))[t];

    // ---- W^T A-fragments in registers (strided global loads, L2-hot)
    f16x8 wfr[2][2];   // [layer][mt]
#pragma unroll
    for (int L=0; L<2; L++){
        const float* W = L ? pw2 : pw1;   // 32x32 row-major [k][n]
#pragma unroll
        for (int mt=0; mt<2; mt++){
            f16x8 a;
#pragma unroll
            for (int e=0; e<8; e++)
                a[e] = (_Float16)W[(8*h+e)*32 + 16*mt + ln];  // W^T[m][k]=W[k][m]
            wfr[L][mt] = a;
        }
    }

    // ---- biases as D-fragment f32x4 (feature = 16mt+4h+q)
    f32x4 b1v[2], b2v[2];
#pragma unroll
    for (int mt=0; mt<2; mt++){
        b1v[mt] = *(const f32x4*)(pb1 + 16*mt + 4*h);
        b2v[mt] = *(const f32x4*)(pb2 + 16*mt + 4*h);
    }

    // ---- pb slices (lane's B-frag k-slice for its 2 pair-tiles), hoisted
    float pbr[2][8];
#pragma unroll
    for (int jj=0; jj<2; jj++){
        const float* q = pb + ((size_t)bnb*PP + 32*w + 16*jj + ln)*HH + 8*h;
        f32x4 v0 = *(const f32x4*)q, v1 = *(const f32x4*)(q+4);
#pragma unroll
        for (int c=0;c<4;c++){ pbr[jj][c]=v0[c]; pbr[jj][4+c]=v1[c]; }
    }
    __syncthreads();   // pas visible to all

#pragma unroll 2
    for (int i = 0; i < 8; i++){
        // ---- H0^T B-fragments straight into registers (fp16)
        float par[8];
        {
            const f32x4* pp = (const f32x4*)(pas + i*32 + 8*h);
            f32x4 v0 = pp[0], v1 = pp[1];
#pragma unroll
            for (int c=0;c<4;c++){ par[c]=v0[c]; par[4+c]=v1[c]; }
        }
        f16x8 bh[2];
#pragma unroll
        for (int jj=0; jj<2; jj++){
            f16x8 b;
#pragma unroll
            for (int e=0; e<8; e++)
                b[e] = (_Float16)elu_f(par[e] + pbr[jj][e]);
            bh[jj] = b;
        }

        // ---- Layer 1: H1^T = W1^T @ H0^T
        f32x4 acc[2][2];
#pragma unroll
        for (int mt=0; mt<2; mt++)
#pragma unroll
        for (int jj=0; jj<2; jj++)
            acc[mt][jj] = __builtin_amdgcn_mfma_f32_16x16x32_f16(
                              wfr[0][mt], bh[jj], b1v[mt], 0,0,0);

        // ---- epilogue -> h1 LDS (b64 writes, wave-local rows, stride 80 B)
#pragma unroll
        for (int mt=0; mt<2; mt++)
#pragma unroll
        for (int jj=0; jj<2; jj++){
            int j = 32*w + 16*jj + ln;
            f16x4 p;
#pragma unroll
            for (int q=0; q<4; q++) p[q] = (_Float16)elu_f(acc[mt][jj][q]);
            *(f16x4*)(h1 + (size_t)j*80 + 32*mt + 8*h) = p;
        }
        // wave-local RAW (each wave reads only its own pairs) -> no barrier

        // ---- Layer 2 B-fragments (b128 reads, features 8h..8h+7)
        f16x8 c2[2];
#pragma unroll
        for (int jj=0; jj<2; jj++)
            c2[jj] = *(const f16x8*)(h1 + (size_t)(32*w + 16*jj + ln)*80 + 16*h);

        // ---- Layer 2 + direct store: jj outer, mt inner so both 64 B halves
        // of each 128 B output line issue back-to-back.
        float* obase = out + ((size_t)(bnb*PP + ic*8 + i))*PP*OUTC;
#pragma unroll
        for (int jj=0; jj<2; jj++){
            int j = 32*w + 16*jj + ln;
#pragma unroll
            for (int mt=0; mt<2; mt++){
                f32x4 c = __builtin_amdgcn_mfma_f32_16x16x32_f16(
                              wfr[1][mt], c2[jj], b2v[mt], 0,0,0);
                f32x4 o;
#pragma unroll
                for (int q=0; q<4; q++) o[q] = elu_f(c[q]);
                *(f32x4*)(obase + (size_t)j*OUTC + 16*mt + 4*h) = o;
            }
        }
        // no barrier: stores drain asynchronously; h1 reuse is wave-local.
    }
}

extern "C" void kernel_launch(void* const* d_in, const int* in_sizes, int n_in,
                              void* d_out, int out_size, void* d_ws, size_t ws_size,
                              hipStream_t stream) {
    const float* x    = (const float*)d_in[0];
    const float* msk  = (const float*)d_in[1];
    const float* nw0  = (const float*)d_in[2];
    const float* nb0  = (const float*)d_in[3];
    const float* nw1  = (const float*)d_in[4];
    const float* nb1  = (const float*)d_in[5];
    const float* nw2  = (const float*)d_in[6];
    const float* nb2  = (const float*)d_in[7];
    const float* pw0  = (const float*)d_in[8];
    const float* pb0  = (const float*)d_in[9];
    const float* pw1  = (const float*)d_in[10];
    const float* pb1  = (const float*)d_in[11];
    const float* pw2  = (const float*)d_in[12];
    const float* pb2  = (const float*)d_in[13];
    float* out = (float*)d_out;

    float* pa = (float*)d_ws;                       // 8192*32 floats = 1 MiB
    float* pb = pa + (size_t)NROWS*HH;              // +1 MiB

    node_kernel<<<NROWS/256, 256, 0, stream>>>(x, msk, nw0, nb0, nw1, nb1,
                                               nw2, nb2, pw0, pb0, pa, pb);
    pair_kernel<<<BB*NBB*16, 256, 0, stream>>>(pa, pb, pw1, pb1,
                                               pw2, pb2, out);
}

// Round 11
// 65.755 us; speedup vs baseline: 11.1358x; 1.0038x over previous
//
#include <hip/hip_runtime.h>

// Problem dims (fixed by reference)
#define BB   2
#define NBB  32
#define PP   128
#define FF   32
#define HH   32
#define NO   8
#define OUTC 32
#define NROWS (BB*NBB*PP)   // 8192

typedef float    f32x4 __attribute__((ext_vector_type(4)));
typedef _Float16 f16x8 __attribute__((ext_vector_type(8)));
typedef _Float16 f16x4 __attribute__((ext_vector_type(4)));
typedef _Float16 f16x2 __attribute__((ext_vector_type(2)));

__device__ __forceinline__ float elu_f(float x){
    return x > 0.0f ? x : (__expf(x) - 1.0f);
}
// packed fp32x2 -> fp16x2 (RTZ), bit-cast to _Float16 vector type
__device__ __forceinline__ f16x2 pk16(float a, float b){
    return __builtin_bit_cast(f16x2, __builtin_amdgcn_cvt_pkrtz(a, b));
}

// Kernel A: node MLP + projection to pa/pb (pair_b0 folded into pa).
__global__ __launch_bounds__(256) void node_kernel(
    const float* __restrict__ x,  const float* __restrict__ msk,
    const float* __restrict__ w0, const float* __restrict__ b0,
    const float* __restrict__ w1, const float* __restrict__ b1,
    const float* __restrict__ w2, const float* __restrict__ b2,
    const float* __restrict__ pw0,const float* __restrict__ pb0,
    float* __restrict__ pa, float* __restrict__ pb)
{
    int row = blockIdx.x*256 + threadIdx.x;
    if (row >= NROWS) return;

    float xr[FF];
    const float4* xp = reinterpret_cast<const float4*>(x + (size_t)row*FF);
#pragma unroll
    for (int q=0;q<FF/4;q++){ float4 v=xp[q]; xr[4*q]=v.x; xr[4*q+1]=v.y; xr[4*q+2]=v.z; xr[4*q+3]=v.w; }

    float h[HH];
#pragma unroll
    for (int k=0;k<HH;k++) h[k]=b0[k];
#pragma unroll
    for (int m=0;m<FF;m++){
        float xm = xr[m];
#pragma unroll
        for (int k=0;k<HH;k++) h[k] += xm * w0[m*HH+k];
    }
#pragma unroll
    for (int k=0;k<HH;k++) h[k]=elu_f(h[k]);

    float g[HH];
#pragma unroll
    for (int k=0;k<HH;k++) g[k]=b1[k];
#pragma unroll
    for (int m=0;m<HH;m++){
        float hm=h[m];
#pragma unroll
        for (int k=0;k<HH;k++) g[k] += hm * w1[m*HH+k];
    }
#pragma unroll
    for (int k=0;k<HH;k++) g[k]=elu_f(g[k]);

    float mk = msk[row];
    float npj[NO];
#pragma unroll
    for (int k=0;k<NO;k++) npj[k]=b2[k];
#pragma unroll
    for (int m=0;m<HH;m++){
        float gm=g[m];
#pragma unroll
        for (int k=0;k<NO;k++) npj[k] += gm * w2[m*NO+k];
    }
#pragma unroll
    for (int k=0;k<NO;k++) npj[k]=elu_f(npj[k])*mk;

    float pav[HH], pbv[HH];
#pragma unroll
    for (int k=0;k<HH;k++){ pav[k]=pb0[k]; pbv[k]=0.0f; }
#pragma unroll
    for (int m=0;m<NO;m++){
        float nm=npj[m];
#pragma unroll
        for (int k=0;k<HH;k++){
            pav[k] += nm * pw0[m*HH+k];
            pbv[k] += nm * pw0[(NO+m)*HH+k];
        }
    }
    float4* pap = reinterpret_cast<float4*>(pa + (size_t)row*HH);
    float4* pbp = reinterpret_cast<float4*>(pb + (size_t)row*HH);
#pragma unroll
    for (int q=0;q<HH/4;q++){
        pap[q]=make_float4(pav[4*q],pav[4*q+1],pav[4*q+2],pav[4*q+3]);
        pbp[q]=make_float4(pbv[4*q],pbv[4*q+1],pbv[4*q+2],pbv[4*q+3]);
    }
}

// ---- Transposed-MFMA pair kernel, fp16, direct D-fragment stores ----
// GEMMs transposed: H1^T = W1^T @ H0^T, O^T = W2^T @ H1^T (mfma 16x16x32_f16).
//   A frag: row m=ln(+16mt), k=8h+{0..7}
//   B frag: col n=pair j=ln(+16jj), k=8h+{0..7}
//   D frag: col n=pair j=ln, row m=feature 16mt+4h+{0..3}  (contiguous x4)
// R9->R10: (1) h1 DOUBLE-BUFFERED by i&1 — the single buffer serialized
// iteration i+1's ds_writes behind iteration i's ds_reads, defeating
// cross-i pipelining (VGPR=128 caps us at 4 waves/SIMD, so ILP across
// iterations is the only latency-hiding left). (2) fp32->fp16 via
// v_cvt_pkrtz (packed, halves cvt count, shortens the chain; RTZ error
// ~2x RNE -> predicted absmax ~0.03 < 0.04625).
// Direct D-frag stores: 16 rows x 64 B full sectors per instr, mt=0/1
// halves of each 128 B line issue back-to-back (no partial-line RMW).
#define SM_PAS  0        // 8 rows * 32 f32 = 1024 B
#define SM_H1   1024     // 2 buffers * (128 rows * 80 B) = 20480
#define SM_SIZE 21504

__global__ __launch_bounds__(256, 4) void pair_kernel(
    const float* __restrict__ pa, const float* __restrict__ pb,
    const float* __restrict__ pw1, const float* __restrict__ pb1,
    const float* __restrict__ pw2, const float* __restrict__ pb2,
    float* __restrict__ out)
{
    __shared__ __align__(16) char smem[SM_SIZE];
    float* pas = (float*)(smem + SM_PAS);

    const int t   = threadIdx.x;
    const int l   = t & 63;
    const int w   = t >> 6;
    const int h   = l >> 4;
    const int ln  = l & 15;
    const int bnb = blockIdx.x >> 4;
    const int ic  = blockIdx.x & 15;

    // ---- stage pa rows for this block's 8 i's (pair_b0 folded)
    if (t < 64)
        ((f32x4*)pas)[t] = ((const f32x4*)(pa + ((size_t)bnb*PP + ic*8)*HH))[t];

    // ---- W^T A-fragments in registers (strided global loads, L2-hot)
    f16x8 wfr[2][2];   // [layer][mt]
#pragma unroll
    for (int L=0; L<2; L++){
        const float* W = L ? pw2 : pw1;   // 32x32 row-major [k][n]
#pragma unroll
        for (int mt=0; mt<2; mt++){
            f16x8 a;
#pragma unroll
            for (int e=0; e<8; e++)
                a[e] = (_Float16)W[(8*h+e)*32 + 16*mt + ln];  // W^T[m][k]=W[k][m]
            wfr[L][mt] = a;
        }
    }

    // ---- biases as D-fragment f32x4 (feature = 16mt+4h+q)
    f32x4 b1v[2], b2v[2];
#pragma unroll
    for (int mt=0; mt<2; mt++){
        b1v[mt] = *(const f32x4*)(pb1 + 16*mt + 4*h);
        b2v[mt] = *(const f32x4*)(pb2 + 16*mt + 4*h);
    }

    // ---- pb slices (lane's B-frag k-slice for its 2 pair-tiles), hoisted
    float pbr[2][8];
#pragma unroll
    for (int jj=0; jj<2; jj++){
        const float* q = pb + ((size_t)bnb*PP + 32*w + 16*jj + ln)*HH + 8*h;
        f32x4 v0 = *(const f32x4*)q, v1 = *(const f32x4*)(q+4);
#pragma unroll
        for (int c=0;c<4;c++){ pbr[jj][c]=v0[c]; pbr[jj][4+c]=v1[c]; }
    }
    __syncthreads();   // pas visible to all

#pragma unroll 2
    for (int i = 0; i < 8; i++){
        char* h1 = smem + SM_H1 + (i & 1)*10240;   // double buffer: i and i+1 independent

        // ---- H0^T B-fragments straight into registers (fp16, packed cvt)
        float par[8];
        {
            const f32x4* pp = (const f32x4*)(pas + i*32 + 8*h);
            f32x4 v0 = pp[0], v1 = pp[1];
#pragma unroll
            for (int c=0;c<4;c++){ par[c]=v0[c]; par[4+c]=v1[c]; }
        }
        f16x8 bh[2];
#pragma unroll
        for (int jj=0; jj<2; jj++){
            float e0[8];
#pragma unroll
            for (int e=0; e<8; e++) e0[e] = elu_f(par[e] + pbr[jj][e]);
            f16x2 p0 = pk16(e0[0], e0[1]);
            f16x2 p1 = pk16(e0[2], e0[3]);
            f16x2 p2 = pk16(e0[4], e0[5]);
            f16x2 p3 = pk16(e0[6], e0[7]);
            f16x8 b = {p0[0],p0[1],p1[0],p1[1],p2[0],p2[1],p3[0],p3[1]};
            bh[jj] = b;
        }

        // ---- Layer 1: H1^T = W1^T @ H0^T
        f32x4 acc[2][2];
#pragma unroll
        for (int mt=0; mt<2; mt++)
#pragma unroll
        for (int jj=0; jj<2; jj++)
            acc[mt][jj] = __builtin_amdgcn_mfma_f32_16x16x32_f16(
                              wfr[0][mt], bh[jj], b1v[mt], 0,0,0);

        // ---- epilogue -> h1 LDS (b64 writes, wave-local rows, stride 80 B)
#pragma unroll
        for (int mt=0; mt<2; mt++)
#pragma unroll
        for (int jj=0; jj<2; jj++){
            int j = 32*w + 16*jj + ln;
            f16x2 q0 = pk16(elu_f(acc[mt][jj][0]), elu_f(acc[mt][jj][1]));
            f16x2 q1 = pk16(elu_f(acc[mt][jj][2]), elu_f(acc[mt][jj][3]));
            f16x4 p = {q0[0],q0[1],q1[0],q1[1]};
            *(f16x4*)(h1 + (size_t)j*80 + 32*mt + 8*h) = p;
        }
        // wave-local RAW (each wave reads only its own pairs) -> no barrier

        // ---- Layer 2 B-fragments (b128 reads, features 8h..8h+7)
        f16x8 c2[2];
#pragma unroll
        for (int jj=0; jj<2; jj++)
            c2[jj] = *(const f16x8*)(h1 + (size_t)(32*w + 16*jj + ln)*80 + 16*h);

        // ---- Layer 2 + direct store: jj outer, mt inner so both 64 B halves
        // of each 128 B output line issue back-to-back.
        float* obase = out + ((size_t)(bnb*PP + ic*8 + i))*PP*OUTC;
#pragma unroll
        for (int jj=0; jj<2; jj++){
            int j = 32*w + 16*jj + ln;
#pragma unroll
            for (int mt=0; mt<2; mt++){
                f32x4 c = __builtin_amdgcn_mfma_f32_16x16x32_f16(
                              wfr[1][mt], c2[jj], b2v[mt], 0,0,0);
                f32x4 o;
#pragma unroll
                for (int q=0; q<4; q++) o[q] = elu_f(c[q]);
                *(f32x4*)(obase + (size_t)j*OUTC + 16*mt + 4*h) = o;
            }
        }
        // no barrier: stores drain asynchronously; h1 reuse is wave-local
        // and double-buffered across i.
    }
}

extern "C" void kernel_launch(void* const* d_in, const int* in_sizes, int n_in,
                              void* d_out, int out_size, void* d_ws, size_t ws_size,
                              hipStream_t stream) {
    const float* x    = (const float*)d_in[0];
    const float* msk  = (const float*)d_in[1];
    const float* nw0  = (const float*)d_in[2];
    const float* nb0  = (const float*)d_in[3];
    const float* nw1  = (const float*)d_in[4];
    const float* nb1  = (const float*)d_in[5];
    const float* nw2  = (const float*)d_in[6];
    const float* nb2  = (const float*)d_in[7];
    const float* pw0  = (const float*)d_in[8];
    const float* pb0  = (const float*)d_in[9];
    const float* pw1  = (const float*)d_in[10];
    const float* pb1  = (const float*)d_in[11];
    const float* pw2  = (const float*)d_in[12];
    const float* pb2  = (const float*)d_in[13];
    float* out = (float*)d_out;

    float* pa = (float*)d_ws;                       // 8192*32 floats = 1 MiB
    float* pb = pa + (size_t)NROWS*HH;              // +1 MiB

    node_kernel<<<NROWS/256, 256, 0, stream>>>(x, msk, nw0, nb0, nw1, nb1,
                                               nw2, nb2, pw0, pb0, pa, pb);
    pair_kernel<<<BB*NBB*16, 256, 0, stream>>>(pa, pb, pw1, pb1,
                                               pw2, pb2, out);
}